// Round 18
// baseline (116.826 us; speedup 1.0000x reference)
//
#include <hip/hip_runtime.h>

typedef unsigned short ushort;
typedef __attribute__((ext_vector_type(4)))  float  f32x4;
typedef __attribute__((ext_vector_type(16))) float  f32x16;
typedef __attribute__((ext_vector_type(8)))  short  s16x8;
typedef __attribute__((ext_vector_type(4)))  ushort u16x4;
typedef __attribute__((ext_vector_type(4)))  unsigned u32x4;

#define MFMA16(a, b, c) __builtin_amdgcn_mfma_f32_16x16x32_bf16((a), (b), (c), 0, 0, 0)
#define MFMA32(a, b, c) __builtin_amdgcn_mfma_f32_32x32x16_bf16((a), (b), (c), 0, 0, 0)

__device__ __forceinline__ ushort f2bf(float f) {
    unsigned u = __builtin_bit_cast(unsigned, f);
    u = (u + 0x7FFF + ((u >> 16) & 1)) >> 16;   // RNE
    return (ushort)u;
}

__device__ __forceinline__ unsigned cvtpk_bf16(float lo, float hi) {
    unsigned r;
    asm("v_cvt_pk_bf16_f32 %0, %1, %2" : "=v"(r) : "v"(lo), "v"(hi));
    return r;
}
// After the swap: a = [a_lo31 | b_lo31], b = [a_hi31 | b_hi31].
// Only safe when a and b are DISTINCT SSA values (regalloc coalescing hazard).
__device__ __forceinline__ void plswap(unsigned& a, unsigned& b) {
    asm volatile("v_permlane32_swap_b32 %0, %1" : "+v"(a), "+v"(b));
}
// Pair (lane ^ 32) reductions via permlane32_swap (pure VALU, no DS op).
__device__ __forceinline__ float pairmax(float x) {
    unsigned a = __builtin_bit_cast(unsigned, x), b;
    asm("v_mov_b32 %0, %1" : "=v"(b) : "v"(a));
    plswap(a, b);
    return fmaxf(__builtin_bit_cast(float, a), __builtin_bit_cast(float, b));
}
__device__ __forceinline__ float pairsum(float x) {
    unsigned a = __builtin_bit_cast(unsigned, x), b;
    asm("v_mov_b32 %0, %1" : "=v"(b) : "v"(a));
    plswap(a, b);
    return __builtin_bit_cast(float, a) + __builtin_bit_cast(float, b);
}
// Raw 2^x. exp() folded to exp2 via Q pre-scale by log2(e).
__device__ __forceinline__ float fast_exp2(float x) {
    float r;
    asm("v_exp_f32 %0, %1" : "=v"(r) : "v"(x));
    return r;
}

__device__ __forceinline__ void gload_lds16(const ushort* g, ushort* l) {
    __builtin_amdgcn_global_load_lds(
        (const __attribute__((address_space(1))) void*)g,
        (__attribute__((address_space(3))) void*)l, 16, 0, 0);
}

// ---------------------------------------------------------------------------
// fp32 -> bf16 conversion for all three inputs in ONE dispatch.
// ---------------------------------------------------------------------------
__global__ __launch_bounds__(256) void cvt_all(
    const float* __restrict__ x, const float* __restrict__ wq,
    const float* __restrict__ wp, ushort* __restrict__ out,
    int n4x, int n4q, int n4p)
{
    int i = blockIdx.x * blockDim.x + threadIdx.x;
    const int stride = gridDim.x * blockDim.x;
    const int total = n4x + n4q + n4p;
    for (; i < total; i += stride) {
        float4 v;
        if (i < n4x)            v = ((const float4*)x)[i];
        else if (i < n4x + n4q) v = ((const float4*)wq)[i - n4x];
        else                    v = ((const float4*)wp)[i - n4x - n4q];
        u16x4 o;
        o[0] = f2bf(v.x); o[1] = f2bf(v.y); o[2] = f2bf(v.z); o[3] = f2bf(v.w);
        ((u16x4*)out)[i] = o;
    }
}

// ---------------------------------------------------------------------------
// 128x128 tile GEMM mainloop, 3-buffer / 2-deep prefetch / counted vmcnt(4),
// slot-XOR bank swizzle. qkv's measured-best structure (607 TF, R11).
// ---------------------------------------------------------------------------
__device__ __forceinline__ void gemm128_mainloop(
    const ushort* __restrict__ A, const ushort* __restrict__ B, int K,
    int row0, int col0, ushort* As, ushort* Bs, f32x4 acc[4][4])
{
    const int t  = threadIdx.x;
    const int l  = t & 63;
    const int w  = t >> 6;
    const int lr = l & 15, lg = l >> 4;
    const int wm = w >> 1, wn = w & 1;

#pragma unroll
    for (int m = 0; m < 4; m++)
#pragma unroll
        for (int n = 0; n < 4; n++) acc[m][n] = (f32x4){0.f, 0.f, 0.f, 0.f};

    const int slot = (t & 3) ^ ((t >> 3) & 3);
    const ushort* ga0 = A + (row0 + (t >> 2)) * K + slot * 8;
    const ushort* gb0 = B + (col0 + (t >> 2)) * K + slot * 8;
    const int rowsz = 64 * K;
    ushort* la0 = As + t * 8;
    ushort* lb0 = Bs + t * 8;

    auto STAGE = [&](int kt, int buf) {
        const int k0  = kt * 32;
        const int off = buf * 4096;
        gload_lds16(ga0 + k0,         la0 + off);
        gload_lds16(ga0 + rowsz + k0, la0 + off + 2048);
        gload_lds16(gb0 + k0,         lb0 + off);
        gload_lds16(gb0 + rowsz + k0, lb0 + off + 2048);
    };
    const int sx = (lg ^ ((lr >> 1) & 3)) * 8;
    auto COMPUTE = [&](int buf) {
        const ushort* Ab = As + buf * 4096;
        const ushort* Bb = Bs + buf * 4096;
        s16x8 af[4], bfr[4];
#pragma unroll
        for (int m = 0; m < 4; m++)
            af[m] = *(const s16x8*)&Ab[(wm * 64 + m * 16 + lr) * 32 + sx];
#pragma unroll
        for (int n = 0; n < 4; n++)
            bfr[n] = *(const s16x8*)&Bb[(wn * 64 + n * 16 + lr) * 32 + sx];
        __builtin_amdgcn_s_setprio(1);
#pragma unroll
        for (int m = 0; m < 4; m++)
#pragma unroll
            for (int n = 0; n < 4; n++)
                acc[m][n] = MFMA16(af[m], bfr[n], acc[m][n]);
        __builtin_amdgcn_s_setprio(0);
    };

    const int nt = K >> 5;          // 24; must be divisible by 3
    STAGE(0, 0);
    STAGE(1, 1);
    asm volatile("s_waitcnt vmcnt(4)" ::: "memory");
    __builtin_amdgcn_s_barrier();

#define GSTEP(IT, CBUF, SBUF)                                          \
    {                                                                  \
        const int sk = (IT) + 2;                                       \
        const bool st = sk < nt;                                       \
        if (st) STAGE(sk, SBUF);                                       \
        COMPUTE(CBUF);                                                 \
        if (st) { asm volatile("s_waitcnt vmcnt(4)" ::: "memory"); }   \
        else    { asm volatile("s_waitcnt vmcnt(0)" ::: "memory"); }   \
        __builtin_amdgcn_s_barrier();                                  \
    }

    for (int base = 0; base < nt; base += 3) {
        GSTEP(base,     0, 2);
        GSTEP(base + 1, 1, 0);
        GSTEP(base + 2, 2, 1);
    }
#undef GSTEP
}

// ---------------------------------------------------------------------------
// Kernel 1: QKV = x @ qkv_w^T, 128x128 tile, 1-D grid 1152 with XCD-affinity
// swizzle: all 18 bc-blocks of one br land on XCD br%8 -> the br's x-tile
// (192KB, re-read 18x) plus all of W (3.5MB) stay L2-resident per XCD.
// Bijective: w = xcd + 8*((br>>3) + 8*bc).
// Scatter into q[bh][n][64] (pre-scaled by SCALE*log2e), k[bh][n][64],
// vT[bh][64][n].
// ---------------------------------------------------------------------------
__global__ __launch_bounds__(256) void qkv_gemm(
    const ushort* __restrict__ X, const ushort* __restrict__ W,
    ushort* __restrict__ qb, ushort* __restrict__ kb, ushort* __restrict__ vb)
{
    __shared__ __align__(16) ushort As[3 * 128 * 32];
    __shared__ __align__(16) ushort Bs[3 * 128 * 32];
    f32x4 acc[4][4];
    const int wg   = blockIdx.x;        // 0..1151
    const int xcd  = wg & 7;
    const int slot = wg >> 3;           // 0..143
    const int br   = xcd + 8 * (slot & 7);   // 0..63
    const int bc   = slot >> 3;              // 0..17
    gemm128_mainloop(X, W, 768, br * 128, bc * 128, As, Bs, acc);

    const int t = threadIdx.x, l = t & 63, w = t >> 6;
    const int lr = l & 15, lg = l >> 4, wm = w >> 1, wn = w & 1;
    const int p = (bc * 128) / 768;
    const int mrow0 = br * 128 + wm * 64 + lg * 4;
    const int ecolB = bc * 128 + wn * 64 + lr;
    const float QSCALE = 0.125f * 1.44269504088896f;  // SCALE * log2(e)

#pragma unroll
    for (int n = 0; n < 4; n++) {
        const int e   = ecolB + n * 16;
        const int rem = e - p * 768;
        const int h   = rem >> 6;
        const int hd  = rem & 63;
#pragma unroll
        for (int m = 0; m < 4; m++) {
            const int mr = mrow0 + m * 16;
            const int b  = mr >> 10;
            const int nn = mr & 1023;
            const f32x4 v = acc[m][n];
            const int bh = b * 12 + h;
            if (p == 0) {
                ushort* dst = qb + (bh * 1024 + nn) * 64 + hd;
#pragma unroll
                for (int r = 0; r < 4; r++) dst[r * 64] = f2bf(v[r] * QSCALE);
            } else if (p == 1) {
                ushort* dst = kb + (bh * 1024 + nn) * 64 + hd;
#pragma unroll
                for (int r = 0; r < 4; r++) dst[r * 64] = f2bf(v[r]);
            } else {
                u16x4 pk;
                pk[0] = f2bf(v[0]); pk[1] = f2bf(v[1]);
                pk[2] = f2bf(v[2]); pk[3] = f2bf(v[3]);
                *(u16x4*)(vb + (bh * 64 + hd) * 1024 + nn) = pk;
            }
        }
    }
}

// ---------------------------------------------------------------------------
// Kernel 2: flash attention — R11 version (measured 44us, best of 6
// structural variants, R12-R15). 32x32 swapped-QK, KVBLK=32; LDS-staged K/V
// (double-buffered, source-side XOR swizzle); softmax fully in-register;
// pair reductions via permlane32_swap. grid (96 bh, 8 qt), block 256.
// (XCD-affinity already by construction: wgid%8 = bh%8.)
// ---------------------------------------------------------------------------
__global__ __launch_bounds__(256) void attn_kernel(
    const ushort* __restrict__ qb, const ushort* __restrict__ kb,
    const ushort* __restrict__ vb, ushort* __restrict__ ao)
{
    __shared__ __align__(16) ushort KV[2][4096];   // [buf][K 2048 | V 2048] = 16KB
    const int bh = blockIdx.x, qt = blockIdx.y;
    const int b = bh / 12, h = bh - b * 12;
    const int t = threadIdx.x, l = t & 63, w = t >> 6;
    const int lq = l & 31, hi = l >> 5;
    const int qr0 = qt * 128 + w * 32;

    // ---- staging source addresses (pre-swizzled) ----
    const int l3 = l >> 3, l7 = l & 7;
    const int ku = w * 8 + l3;                      // LDS row this lane fills
    const int pfv = l7 ^ l3;                        // swizzled 16B slot index
    const char* ksrc = (const char*)kb + (size_t)(bh * 1024 + ku) * 128
                     + ((l7 ^ l3) << 4);            // + kv0*128 per iter
    const char* vsrc = (const char*)vb + (size_t)(bh * 64 + ku + 32 * ((pfv >> 2) & 1)) * 2048
                     + ((pfv & 3) << 4);            // + kv0*2 per iter
    ushort* kdst = &KV[0][0]    + w * 512 + l * 8;  // uniform base + lane*16B
    ushort* vdst = &KV[0][2048] + w * 512 + l * 8;

    // ---- Q fragments (B-operand): col=q=lq, k=d-slice s*16 + hi*8 ----
    const ushort* qlane = qb + (bh * 1024 + qr0 + lq) * 64 + hi * 8;
    s16x8 qf[4];
#pragma unroll
    for (int s = 0; s < 4; s++) qf[s] = *(const s16x8*)(qlane + s * 16);

    float m = -__builtin_inff();
    float lsum = 0.f;
    f32x16 o0 = {}, o1 = {};

    // prologue: stage tile 0 into buf 0
    gload_lds16((const ushort*)ksrc, kdst);
    gload_lds16((const ushort*)vsrc, vdst);
    __syncthreads();

    const int fx = (lq & 7) << 4;                   // read-side swizzle
    for (int it = 0; it < 32; ++it) {
        const int cur = it & 1;
        // ---- prefetch next tile into the other buffer ----
        if (it < 31) {
            const int kvn = (it + 1) * 32;
            gload_lds16((const ushort*)(ksrc + kvn * 128), kdst + (cur ^ 1) * 4096);
            gload_lds16((const ushort*)(vsrc + kvn * 2),   vdst + (cur ^ 1) * 4096);
        }
        const char* Kb = (const char*)&KV[cur][0];
        const char* Vb = (const char*)&KV[cur][2048];

        // ---- K fragments (A-operand): row kv=lq, d-slice s*16+hi*8 ----
        s16x8 kf[4];
#pragma unroll
        for (int s = 0; s < 4; s++)
            kf[s] = *(const s16x8*)(Kb + lq * 128 + ((hi * 16 + s * 32) ^ fx));

        f32x16 sa = {};
        __builtin_amdgcn_s_setprio(1);
#pragma unroll
        for (int s = 0; s < 4; s++) sa = MFMA32(kf[s], qf[s], sa);
        __builtin_amdgcn_s_setprio(0);

        // ---- in-register online softmax (16 k/lane, pair lane has rest) ----
        float g0 = fmaxf(fmaxf(sa[0],  sa[1]),  sa[2]);
        float g1 = fmaxf(fmaxf(sa[3],  sa[4]),  sa[5]);
        float g2 = fmaxf(fmaxf(sa[6],  sa[7]),  sa[8]);
        float g3 = fmaxf(fmaxf(sa[9],  sa[10]), sa[11]);
        float g4 = fmaxf(fmaxf(sa[12], sa[13]), sa[14]);
        float h0 = fmaxf(fmaxf(g0, g1), g2);
        float h1 = fmaxf(fmaxf(g3, g4), sa[15]);
        const float mx = pairmax(fmaxf(h0, h1));

        if (!__all(mx <= m + 8.f)) {          // defer-max (T13), log2 units
            const float mn = fmaxf(m, mx);
            const float fac = fast_exp2(m - mn);
            m = mn;
            lsum *= fac;
#pragma unroll
            for (int r = 0; r < 16; r++) { o0[r] *= fac; o1[r] *= fac; }
        }

        float p[16];
#pragma unroll
        for (int r = 0; r < 16; r++) p[r] = fast_exp2(sa[r] - m);
        float ts[8];
#pragma unroll
        for (int r = 0; r < 8; r++) ts[r] = p[r] + p[r + 8];
#pragma unroll
        for (int s = 4; s; s >>= 1)
#pragma unroll
            for (int r = 0; r < s; r++) ts[r] += ts[r + s];
        lsum += pairsum(ts[0]);

        // ---- pack P^T into PV B-fragments (cvt_pk + permlane32_swap) ----
        s16x8 pfr[2];
#pragma unroll
        for (int slot = 0; slot < 2; slot++) {
            const int r0 = slot * 8;
            unsigned a0 = cvtpk_bf16(p[r0 + 0], p[r0 + 1]);
            unsigned a1 = cvtpk_bf16(p[r0 + 4], p[r0 + 5]);
            plswap(a0, a1);
            unsigned b0 = cvtpk_bf16(p[r0 + 2], p[r0 + 3]);
            unsigned b1 = cvtpk_bf16(p[r0 + 6], p[r0 + 7]);
            plswap(b0, b1);
            const u32x4 u = {a0, b0, a1, b1};
            pfr[slot] = __builtin_bit_cast(s16x8, u);
        }

        // ---- V fragments + PV: O^T += V^T * P^T ----
        s16x8 vf[2][2];   // [half d0/d32][k-slot]
#pragma unroll
        for (int half = 0; half < 2; half++)
#pragma unroll
            for (int s = 0; s < 2; s++)
                vf[half][s] = *(const s16x8*)(Vb + lq * 128 + ((half * 64 + hi * 16 + s * 32) ^ fx));
        __builtin_amdgcn_s_setprio(1);
        o0 = MFMA32(vf[0][0], pfr[0], o0);
        o1 = MFMA32(vf[1][0], pfr[0], o1);
        o0 = MFMA32(vf[0][1], pfr[1], o0);
        o1 = MFMA32(vf[1][1], pfr[1], o1);
        __builtin_amdgcn_s_setprio(0);

        __syncthreads();   // drains prefetch (vmcnt) + all reads of cur buf
    }

    // ---- epilogue: out[b][q][h*64+d] = O^T[d][q] / lsum ----
    const float inv = 1.f / lsum;
    ushort* op = ao + (b * 1024 + qr0 + lq) * 768 + h * 64 + 4 * hi;
#pragma unroll
    for (int i = 0; i < 4; i++) {
        u16x4 pk0, pk1;
#pragma unroll
        for (int j = 0; j < 4; j++) {
            pk0[j] = f2bf(o0[4 * i + j] * inv);
            pk1[j] = f2bf(o1[4 * i + j] * inv);
        }
        *(u16x4*)(op + 8 * i)      = pk0;   // d = 8i+4hi + 0..3
        *(u16x4*)(op + 32 + 8 * i) = pk1;   // d = 32 + 8i+4hi + 0..3
    }
}

// ---------------------------------------------------------------------------
// Kernel 3: out = attn_out @ proj_w^T + proj_b (fp32 out). 64x128 tile,
// 3-buffer / vmcnt(3); 1-D grid 768 with the same XCD-affinity swizzle:
// all 6 bc-blocks of one br share an XCD (A-rows + W L2-resident).
// ---------------------------------------------------------------------------
__global__ __launch_bounds__(256) void proj_gemm(
    const ushort* __restrict__ A, const ushort* __restrict__ W,
    const float* __restrict__ bias, float* __restrict__ out)
{
    __shared__ __align__(16) ushort As[3 * 64 * 32];
    __shared__ __align__(16) ushort Bs[3 * 128 * 32];
    const int t = threadIdx.x, l = t & 63, w = t >> 6;
    const int lr = l & 15, lg = l >> 4;
    const int wm = w >> 1, wn = w & 1;
    const int wg   = blockIdx.x;        // 0..767
    const int xcd  = wg & 7;
    const int slot = wg >> 3;           // 0..95
    const int br   = xcd + 8 * (slot & 15);  // 0..127
    const int bc   = slot >> 4;              // 0..5

    f32x4 acc[2][4];
#pragma unroll
    for (int m = 0; m < 2; m++)
#pragma unroll
        for (int n = 0; n < 4; n++) acc[m][n] = (f32x4){0.f, 0.f, 0.f, 0.f};

    const int slt = (t & 3) ^ ((t >> 3) & 3);
    const ushort* ga0 = A + (br * 64 + (t >> 2)) * 768 + slt * 8;
    const ushort* gb0 = W + (bc * 128 + (t >> 2)) * 768 + slt * 8;
    ushort* la0 = As + t * 8;
    ushort* lb0 = Bs + t * 8;

    auto STAGE = [&](int kt, int buf) {
        const int k0 = kt * 32;
        gload_lds16(ga0 + k0,            la0 + buf * 2048);
        gload_lds16(gb0 + k0,            lb0 + buf * 4096);
        gload_lds16(gb0 + 64 * 768 + k0, lb0 + buf * 4096 + 2048);
    };
    const int sx = (lg ^ ((lr >> 1) & 3)) * 8;
    auto COMPUTE = [&](int buf) {
        const ushort* Ab = As + buf * 2048;
        const ushort* Bb = Bs + buf * 4096;
        s16x8 af[2], bfr[4];
#pragma unroll
        for (int m = 0; m < 2; m++)
            af[m] = *(const s16x8*)&Ab[(wm * 32 + m * 16 + lr) * 32 + sx];
#pragma unroll
        for (int n = 0; n < 4; n++)
            bfr[n] = *(const s16x8*)&Bb[(wn * 64 + n * 16 + lr) * 32 + sx];
        __builtin_amdgcn_s_setprio(1);
#pragma unroll
        for (int m = 0; m < 2; m++)
#pragma unroll
            for (int n = 0; n < 4; n++)
                acc[m][n] = MFMA16(af[m], bfr[n], acc[m][n]);
        __builtin_amdgcn_s_setprio(0);
    };

    const int nt = 24;
    STAGE(0, 0);
    STAGE(1, 1);
    asm volatile("s_waitcnt vmcnt(3)" ::: "memory");
    __builtin_amdgcn_s_barrier();

#define GSTEP(IT, CBUF, SBUF)                                          \
    {                                                                  \
        const int sk = (IT) + 2;                                       \
        const bool st = sk < nt;                                       \
        if (st) STAGE(sk, SBUF);                                       \
        COMPUTE(CBUF);                                                 \
        if (st) { asm volatile("s_waitcnt vmcnt(3)" ::: "memory"); }   \
        else    { asm volatile("s_waitcnt vmcnt(0)" ::: "memory"); }   \
        __builtin_amdgcn_s_barrier();                                  \
    }

    for (int base = 0; base < nt; base += 3) {
        GSTEP(base,     0, 2);
        GSTEP(base + 1, 1, 0);
        GSTEP(base + 2, 2, 1);
    }
#undef GSTEP

    const int mrow0 = br * 64 + wm * 32 + lg * 4;
    const int ecolB = bc * 128 + wn * 64 + lr;
#pragma unroll
    for (int n = 0; n < 4; n++) {
        const int e = ecolB + n * 16;
        const float bv = bias[e];
#pragma unroll
        for (int m = 0; m < 2; m++) {
            const int mr = mrow0 + m * 16;
#pragma unroll
            for (int r = 0; r < 4; r++)
                out[(mr + r) * 768 + e] = acc[m][n][r] + bv;
        }
    }
}

// ---------------------------------------------------------------------------
extern "C" void kernel_launch(void* const* d_in, const int* in_sizes, int n_in,
                              void* d_out, int out_size, void* d_ws, size_t ws_size,
                              hipStream_t stream)
{
    const float* x  = (const float*)d_in[0];   // [8,1024,768] f32
    const float* wq = (const float*)d_in[1];   // [2304,768]   f32
    const float* wp = (const float*)d_in[2];   // [768,768]    f32
    const float* pb = (const float*)d_in[3];   // [768]        f32
    float* out = (float*)d_out;                // [8,1024,768] f32

    const int NX = 8 * 1024 * 768;             // 6291456
    const int NQ = 2304 * 768;                 // 1769472
    const int NP = 768 * 768;                  // 589824
    const int SEG = 8 * 12 * 1024 * 64;        // 6291456

    ushort* xb  = (ushort*)d_ws;               // x bf16; reused as ao after qkv
    ushort* wqb = xb + NX;
    ushort* wpb = wqb + NQ;
    ushort* qb  = wpb + NP;                    // q  [bh][n][64]  (pre-scaled)
    ushort* kb  = qb + SEG;                    // k  [bh][n][64]
    ushort* vb  = kb + SEG;                    // vT [bh][64][n]
    ushort* ao  = xb;                          // attn out aliases xb (dead by then)

    cvt_all<<<2048, 256, 0, stream>>>(x, wq, wp, xb, NX / 4, NQ / 4, NP / 4);

    qkv_gemm  <<<1152, 256, 0, stream>>>(xb, wqb, qb, kb, vb);
    attn_kernel<<<dim3(96, 8), 256, 0, stream>>>(qb, kb, vb, ao);
    proj_gemm <<<768, 256, 0, stream>>>(ao, wpb, pb, out);
}

// Round 19
// 114.630 us; speedup vs baseline: 1.0192x; 1.0192x over previous
//
#include <hip/hip_runtime.h>

typedef unsigned short ushort;
typedef __attribute__((ext_vector_type(4)))  float  f32x4;
typedef __attribute__((ext_vector_type(16))) float  f32x16;
typedef __attribute__((ext_vector_type(8)))  short  s16x8;
typedef __attribute__((ext_vector_type(4)))  ushort u16x4;
typedef __attribute__((ext_vector_type(4)))  unsigned u32x4;

#define MFMA16(a, b, c) __builtin_amdgcn_mfma_f32_16x16x32_bf16((a), (b), (c), 0, 0, 0)
#define MFMA32(a, b, c) __builtin_amdgcn_mfma_f32_32x32x16_bf16((a), (b), (c), 0, 0, 0)

__device__ __forceinline__ ushort f2bf(float f) {
    unsigned u = __builtin_bit_cast(unsigned, f);
    u = (u + 0x7FFF + ((u >> 16) & 1)) >> 16;   // RNE
    return (ushort)u;
}

__device__ __forceinline__ unsigned cvtpk_bf16(float lo, float hi) {
    unsigned r;
    asm("v_cvt_pk_bf16_f32 %0, %1, %2" : "=v"(r) : "v"(lo), "v"(hi));
    return r;
}
// After the swap: a = [a_lo31 | b_lo31], b = [a_hi31 | b_hi31].
// Only safe when a and b are DISTINCT SSA values (regalloc coalescing hazard).
__device__ __forceinline__ void plswap(unsigned& a, unsigned& b) {
    asm volatile("v_permlane32_swap_b32 %0, %1" : "+v"(a), "+v"(b));
}
// Pair (lane ^ 32) reductions via permlane32_swap (pure VALU, no DS op).
__device__ __forceinline__ float pairmax(float x) {
    unsigned a = __builtin_bit_cast(unsigned, x), b;
    asm("v_mov_b32 %0, %1" : "=v"(b) : "v"(a));
    plswap(a, b);
    return fmaxf(__builtin_bit_cast(float, a), __builtin_bit_cast(float, b));
}
__device__ __forceinline__ float pairsum(float x) {
    unsigned a = __builtin_bit_cast(unsigned, x), b;
    asm("v_mov_b32 %0, %1" : "=v"(b) : "v"(a));
    plswap(a, b);
    return __builtin_bit_cast(float, a) + __builtin_bit_cast(float, b);
}
// Raw 2^x. exp() folded to exp2 via Q pre-scale by log2(e).
__device__ __forceinline__ float fast_exp2(float x) {
    float r;
    asm("v_exp_f32 %0, %1" : "=v"(r) : "v"(x));
    return r;
}

__device__ __forceinline__ void gload_lds16(const ushort* g, ushort* l) {
    __builtin_amdgcn_global_load_lds(
        (const __attribute__((address_space(1))) void*)g,
        (__attribute__((address_space(3))) void*)l, 16, 0, 0);
}

// ---------------------------------------------------------------------------
// fp32 -> bf16 conversion for all three inputs in ONE dispatch.
// ---------------------------------------------------------------------------
__global__ __launch_bounds__(256) void cvt_all(
    const float* __restrict__ x, const float* __restrict__ wq,
    const float* __restrict__ wp, ushort* __restrict__ out,
    int n4x, int n4q, int n4p)
{
    int i = blockIdx.x * blockDim.x + threadIdx.x;
    const int stride = gridDim.x * blockDim.x;
    const int total = n4x + n4q + n4p;
    for (; i < total; i += stride) {
        float4 v;
        if (i < n4x)            v = ((const float4*)x)[i];
        else if (i < n4x + n4q) v = ((const float4*)wq)[i - n4x];
        else                    v = ((const float4*)wp)[i - n4x - n4q];
        u16x4 o;
        o[0] = f2bf(v.x); o[1] = f2bf(v.y); o[2] = f2bf(v.z); o[3] = f2bf(v.w);
        ((u16x4*)out)[i] = o;
    }
}

// ---------------------------------------------------------------------------
// 128x128 tile GEMM mainloop, 3-buffer / 2-deep prefetch / counted vmcnt(4),
// slot-XOR bank swizzle. Measured-best GEMM structure (607 TF, R11).
// ---------------------------------------------------------------------------
__device__ __forceinline__ void gemm128_mainloop(
    const ushort* __restrict__ A, const ushort* __restrict__ B, int K,
    int row0, int col0, ushort* As, ushort* Bs, f32x4 acc[4][4])
{
    const int t  = threadIdx.x;
    const int l  = t & 63;
    const int w  = t >> 6;
    const int lr = l & 15, lg = l >> 4;
    const int wm = w >> 1, wn = w & 1;

#pragma unroll
    for (int m = 0; m < 4; m++)
#pragma unroll
        for (int n = 0; n < 4; n++) acc[m][n] = (f32x4){0.f, 0.f, 0.f, 0.f};

    const int slot = (t & 3) ^ ((t >> 3) & 3);
    const ushort* ga0 = A + (row0 + (t >> 2)) * K + slot * 8;
    const ushort* gb0 = B + (col0 + (t >> 2)) * K + slot * 8;
    const int rowsz = 64 * K;
    ushort* la0 = As + t * 8;
    ushort* lb0 = Bs + t * 8;

    auto STAGE = [&](int kt, int buf) {
        const int k0  = kt * 32;
        const int off = buf * 4096;
        gload_lds16(ga0 + k0,         la0 + off);
        gload_lds16(ga0 + rowsz + k0, la0 + off + 2048);
        gload_lds16(gb0 + k0,         lb0 + off);
        gload_lds16(gb0 + rowsz + k0, lb0 + off + 2048);
    };
    const int sx = (lg ^ ((lr >> 1) & 3)) * 8;
    auto COMPUTE = [&](int buf) {
        const ushort* Ab = As + buf * 4096;
        const ushort* Bb = Bs + buf * 4096;
        s16x8 af[4], bfr[4];
#pragma unroll
        for (int m = 0; m < 4; m++)
            af[m] = *(const s16x8*)&Ab[(wm * 64 + m * 16 + lr) * 32 + sx];
#pragma unroll
        for (int n = 0; n < 4; n++)
            bfr[n] = *(const s16x8*)&Bb[(wn * 64 + n * 16 + lr) * 32 + sx];
        __builtin_amdgcn_s_setprio(1);
#pragma unroll
        for (int m = 0; m < 4; m++)
#pragma unroll
            for (int n = 0; n < 4; n++)
                acc[m][n] = MFMA16(af[m], bfr[n], acc[m][n]);
        __builtin_amdgcn_s_setprio(0);
    };

    const int nt = K >> 5;          // 24; must be divisible by 3
    STAGE(0, 0);
    STAGE(1, 1);
    asm volatile("s_waitcnt vmcnt(4)" ::: "memory");
    __builtin_amdgcn_s_barrier();

#define GSTEP(IT, CBUF, SBUF)                                          \
    {                                                                  \
        const int sk = (IT) + 2;                                       \
        const bool st = sk < nt;                                       \
        if (st) STAGE(sk, SBUF);                                       \
        COMPUTE(CBUF);                                                 \
        if (st) { asm volatile("s_waitcnt vmcnt(4)" ::: "memory"); }   \
        else    { asm volatile("s_waitcnt vmcnt(0)" ::: "memory"); }   \
        __builtin_amdgcn_s_barrier();                                  \
    }

    for (int base = 0; base < nt; base += 3) {
        GSTEP(base,     0, 2);
        GSTEP(base + 1, 1, 0);
        GSTEP(base + 2, 2, 1);
    }
#undef GSTEP
}

// ---------------------------------------------------------------------------
// Kernel 1: QKV = x @ qkv_w^T, 128x128 tile, grid (64, 18), block 256.
// Scatter into q[bh][n][64] (pre-scaled by SCALE*log2e), k[bh][n][64],
// vT[bh][64][n].  (R11 exact — measured best: 47.8us.)
// ---------------------------------------------------------------------------
__global__ __launch_bounds__(256) void qkv_gemm(
    const ushort* __restrict__ X, const ushort* __restrict__ W,
    ushort* __restrict__ qb, ushort* __restrict__ kb, ushort* __restrict__ vb)
{
    __shared__ __align__(16) ushort As[3 * 128 * 32];
    __shared__ __align__(16) ushort Bs[3 * 128 * 32];
    f32x4 acc[4][4];
    const int br = blockIdx.x, bc = blockIdx.y;
    gemm128_mainloop(X, W, 768, br * 128, bc * 128, As, Bs, acc);

    const int t = threadIdx.x, l = t & 63, w = t >> 6;
    const int lr = l & 15, lg = l >> 4, wm = w >> 1, wn = w & 1;
    const int p = (bc * 128) / 768;
    const int mrow0 = br * 128 + wm * 64 + lg * 4;
    const int ecolB = bc * 128 + wn * 64 + lr;
    const float QSCALE = 0.125f * 1.44269504088896f;  // SCALE * log2(e)

#pragma unroll
    for (int n = 0; n < 4; n++) {
        const int e   = ecolB + n * 16;
        const int rem = e - p * 768;
        const int h   = rem >> 6;
        const int hd  = rem & 63;
#pragma unroll
        for (int m = 0; m < 4; m++) {
            const int mr = mrow0 + m * 16;
            const int b  = mr >> 10;
            const int nn = mr & 1023;
            const f32x4 v = acc[m][n];
            const int bh = b * 12 + h;
            if (p == 0) {
                ushort* dst = qb + (bh * 1024 + nn) * 64 + hd;
#pragma unroll
                for (int r = 0; r < 4; r++) dst[r * 64] = f2bf(v[r] * QSCALE);
            } else if (p == 1) {
                ushort* dst = kb + (bh * 1024 + nn) * 64 + hd;
#pragma unroll
                for (int r = 0; r < 4; r++) dst[r * 64] = f2bf(v[r]);
            } else {
                u16x4 pk;
                pk[0] = f2bf(v[0]); pk[1] = f2bf(v[1]);
                pk[2] = f2bf(v[2]); pk[3] = f2bf(v[3]);
                *(u16x4*)(vb + (bh * 64 + hd) * 1024 + nn) = pk;
            }
        }
    }
}

// ---------------------------------------------------------------------------
// Kernel 2: flash attention — R11 inner loop verbatim, but 64 kv staged per
// barrier (two sequential 32-kv passes between syncs): halves the barrier +
// full-drain count with bit-identical math. LDS 2 x 16KB = 32KB
// ([K0|V0|K1|V1] per buffer, 4KB regions, R15's verified staging addressing
// with the second sub-tile at +32 kv rows). grid (96 bh, 8 qt), block 256.
// ---------------------------------------------------------------------------
__global__ __launch_bounds__(256) void attn_kernel(
    const ushort* __restrict__ qb, const ushort* __restrict__ kb,
    const ushort* __restrict__ vb, ushort* __restrict__ ao)
{
    __shared__ __align__(16) ushort KV[2][8192];   // [buf][K0|V0|K1|V1] = 32KB
    const int bh = blockIdx.x, qt = blockIdx.y;
    const int b = bh / 12, h = bh - b * 12;
    const int t = threadIdx.x, l = t & 63, w = t >> 6;
    const int lq = l & 31, hi = l >> 5;
    const int qr0 = qt * 128 + w * 32;

    // ---- staging sources (pre-swizzled): thread t fills LDS row u = t>>3,
    //      phys 16B-slot t&7 of each 4KB region; source slot = (t&7)^(u&7).
    const int u   = t >> 3;                         // 0..31
    const int pfv = (t & 7) ^ (u & 7);
    const char* ksrc = (const char*)kb + (size_t)(bh * 1024 + u) * 128 + (pfv << 4);
    const char* vsrc = (const char*)vb
                     + (size_t)(bh * 64 + u + 32 * ((pfv >> 2) & 1)) * 2048
                     + ((pfv & 3) << 4);
    ushort* kd0 = &KV[0][0]    + t * 8;
    ushort* vd0 = &KV[0][2048] + t * 8;
    ushort* kd1 = &KV[0][4096] + t * 8;
    ushort* vd1 = &KV[0][6144] + t * 8;

    // 64-kv tile kt: sub0 = kv rows kt*64..+31, sub1 = +32..+63.
    auto STAGE = [&](int kt, int buf) {
        const int bo = buf * 8192;
        gload_lds16((const ushort*)(ksrc + (size_t)kt * 8192),        kd0 + bo);
        gload_lds16((const ushort*)(vsrc + kt * 128),                 vd0 + bo);
        gload_lds16((const ushort*)(ksrc + (size_t)kt * 8192 + 4096), kd1 + bo);
        gload_lds16((const ushort*)(vsrc + kt * 128 + 64),            vd1 + bo);
    };

    // ---- Q fragments (B-operand): col=q=lq, k=d-slice s*16 + hi*8 ----
    const ushort* qlane = qb + (bh * 1024 + qr0 + lq) * 64 + hi * 8;
    s16x8 qf[4];
#pragma unroll
    for (int s = 0; s < 4; s++) qf[s] = *(const s16x8*)(qlane + s * 16);

    float m = -__builtin_inff();
    float lsum = 0.f;
    f32x16 o0 = {}, o1 = {};

    // prologue: stage 64-kv tile 0 into buf 0
    STAGE(0, 0);
    __syncthreads();

    const int fx = (lq & 7) << 4;                   // read-side swizzle
    for (int it = 0; it < 16; ++it) {
        const int cur = it & 1;
        if (it < 15) STAGE(it + 1, cur ^ 1);

#pragma unroll
        for (int sub = 0; sub < 2; ++sub) {
            const char* Kb = (const char*)&KV[cur][0] + sub * 8192;
            const char* Vb = Kb + 4096;

            // ---- K fragments (A-operand): row kv=lq, d-slice s*16+hi*8 ----
            s16x8 kf[4];
#pragma unroll
            for (int s = 0; s < 4; s++)
                kf[s] = *(const s16x8*)(Kb + lq * 128 + ((hi * 16 + s * 32) ^ fx));

            f32x16 sa = {};
            __builtin_amdgcn_s_setprio(1);
#pragma unroll
            for (int s = 0; s < 4; s++) sa = MFMA32(kf[s], qf[s], sa);
            __builtin_amdgcn_s_setprio(0);

            // ---- in-register online softmax ----
            float g0 = fmaxf(fmaxf(sa[0],  sa[1]),  sa[2]);
            float g1 = fmaxf(fmaxf(sa[3],  sa[4]),  sa[5]);
            float g2 = fmaxf(fmaxf(sa[6],  sa[7]),  sa[8]);
            float g3 = fmaxf(fmaxf(sa[9],  sa[10]), sa[11]);
            float g4 = fmaxf(fmaxf(sa[12], sa[13]), sa[14]);
            float h0 = fmaxf(fmaxf(g0, g1), g2);
            float h1 = fmaxf(fmaxf(g3, g4), sa[15]);
            const float mx = pairmax(fmaxf(h0, h1));

            if (!__all(mx <= m + 8.f)) {          // defer-max (T13), log2 units
                const float mn = fmaxf(m, mx);
                const float fac = fast_exp2(m - mn);
                m = mn;
                lsum *= fac;
#pragma unroll
                for (int r = 0; r < 16; r++) { o0[r] *= fac; o1[r] *= fac; }
            }

            float p[16];
#pragma unroll
            for (int r = 0; r < 16; r++) p[r] = fast_exp2(sa[r] - m);
            float ts[8];
#pragma unroll
            for (int r = 0; r < 8; r++) ts[r] = p[r] + p[r + 8];
#pragma unroll
            for (int s = 4; s; s >>= 1)
#pragma unroll
                for (int r = 0; r < s; r++) ts[r] += ts[r + s];
            lsum += pairsum(ts[0]);

            // ---- pack P^T into PV B-fragments (cvt_pk + permlane32_swap) ----
            s16x8 pfr[2];
#pragma unroll
            for (int slot = 0; slot < 2; slot++) {
                const int r0 = slot * 8;
                unsigned a0 = cvtpk_bf16(p[r0 + 0], p[r0 + 1]);
                unsigned a1 = cvtpk_bf16(p[r0 + 4], p[r0 + 5]);
                plswap(a0, a1);
                unsigned b0 = cvtpk_bf16(p[r0 + 2], p[r0 + 3]);
                unsigned b1 = cvtpk_bf16(p[r0 + 6], p[r0 + 7]);
                plswap(b0, b1);
                const u32x4 uu = {a0, b0, a1, b1};
                pfr[slot] = __builtin_bit_cast(s16x8, uu);
            }

            // ---- V fragments + PV: O^T += V^T * P^T ----
            s16x8 vf[2][2];   // [half d0/d32][k-slot]
#pragma unroll
            for (int hd = 0; hd < 2; hd++)
#pragma unroll
                for (int s = 0; s < 2; s++)
                    vf[hd][s] = *(const s16x8*)(Vb + lq * 128 + ((hd * 64 + hi * 16 + s * 32) ^ fx));
            __builtin_amdgcn_s_setprio(1);
            o0 = MFMA32(vf[0][0], pfr[0], o0);
            o1 = MFMA32(vf[1][0], pfr[0], o1);
            o0 = MFMA32(vf[0][1], pfr[1], o0);
            o1 = MFMA32(vf[1][1], pfr[1], o1);
            __builtin_amdgcn_s_setprio(0);
        }

        __syncthreads();   // drains prefetch (vmcnt) + all reads of cur buf
    }

    // ---- epilogue: out[b][q][h*64+d] = O^T[d][q] / lsum ----
    const float inv = 1.f / lsum;
    ushort* op = ao + (b * 1024 + qr0 + lq) * 768 + h * 64 + 4 * hi;
#pragma unroll
    for (int i = 0; i < 4; i++) {
        u16x4 pk0, pk1;
#pragma unroll
        for (int j = 0; j < 4; j++) {
            pk0[j] = f2bf(o0[4 * i + j] * inv);
            pk1[j] = f2bf(o1[4 * i + j] * inv);
        }
        *(u16x4*)(op + 8 * i)      = pk0;   // d = 8i+4hi + 0..3
        *(u16x4*)(op + 32 + 8 * i) = pk1;   // d = 32 + 8i+4hi + 0..3
    }
}

// ---------------------------------------------------------------------------
// Kernel 3: out = attn_out @ proj_w^T + proj_b (fp32 out). 128x128 tile,
// grid (64, 6). (R11 exact — best-measured total config.)
// ---------------------------------------------------------------------------
__global__ __launch_bounds__(256) void proj_gemm(
    const ushort* __restrict__ A, const ushort* __restrict__ W,
    const float* __restrict__ bias, float* __restrict__ out)
{
    __shared__ __align__(16) ushort As[3 * 128 * 32];
    __shared__ __align__(16) ushort Bs[3 * 128 * 32];
    f32x4 acc[4][4];
    const int br = blockIdx.x, bc = blockIdx.y;
    gemm128_mainloop(A, W, 768, br * 128, bc * 128, As, Bs, acc);

    const int t = threadIdx.x, l = t & 63, w = t >> 6;
    const int lr = l & 15, lg = l >> 4, wm = w >> 1, wn = w & 1;
    const int mrow0 = br * 128 + wm * 64 + lg * 4;
    const int ecolB = bc * 128 + wn * 64 + lr;

#pragma unroll
    for (int n = 0; n < 4; n++) {
        const int e = ecolB + n * 16;
        const float bv = bias[e];
#pragma unroll
        for (int m = 0; m < 4; m++) {
            const int mr = mrow0 + m * 16;
#pragma unroll
            for (int r = 0; r < 4; r++)
                out[(mr + r) * 768 + e] = acc[m][n][r] + bv;
        }
    }
}

// ---------------------------------------------------------------------------
extern "C" void kernel_launch(void* const* d_in, const int* in_sizes, int n_in,
                              void* d_out, int out_size, void* d_ws, size_t ws_size,
                              hipStream_t stream)
{
    const float* x  = (const float*)d_in[0];   // [8,1024,768] f32
    const float* wq = (const float*)d_in[1];   // [2304,768]   f32
    const float* wp = (const float*)d_in[2];   // [768,768]    f32
    const float* pb = (const float*)d_in[3];   // [768]        f32
    float* out = (float*)d_out;                // [8,1024,768] f32

    const int NX = 8 * 1024 * 768;             // 6291456
    const int NQ = 2304 * 768;                 // 1769472
    const int NP = 768 * 768;                  // 589824
    const int SEG = 8 * 12 * 1024 * 64;        // 6291456

    ushort* xb  = (ushort*)d_ws;               // x bf16; reused as ao after qkv
    ushort* wqb = xb + NX;
    ushort* wpb = wqb + NQ;
    ushort* qb  = wpb + NP;                    // q  [bh][n][64]  (pre-scaled)
    ushort* kb  = qb + SEG;                    // k  [bh][n][64]
    ushort* vb  = kb + SEG;                    // vT [bh][64][n]
    ushort* ao  = xb;                          // attn out aliases xb (dead by then)

    cvt_all<<<2048, 256, 0, stream>>>(x, wq, wp, xb, NX / 4, NQ / 4, NP / 4);

    qkv_gemm  <<<dim3(64, 18), 256, 0, stream>>>(xb, wqb, qb, kb, vb);
    attn_kernel<<<dim3(96, 8), 256, 0, stream>>>(qb, kb, vb, ao);
    proj_gemm <<<dim3(64, 6), 256, 0, stream>>>(ao, wpb, pb, out);
}